// Round 4
// baseline (49.573 us; speedup 1.0000x reference)
//
#include <hip/hip_runtime.h>

// DSSIM loss: y_pred, y_true [8,3,512,512] fp32 -> scalar mean DSSIM.
// PXT=4: thread owns 4 cols; wave = half row (64 lanes x 4 = 256 cols);
// block = 256 threads = 4 waves = 2 full rows. 18 aligned float4 loads/thread.
// Halo column sums: interior lanes via one post-loop shfl of accumulated sums;
// the half-row boundary (col 255/256) via an 80B LDS exchange within the block.
// Max occupancy: 2048 blocks = 8192 waves = 32 waves/CU.

#define N_IMG 8
#define C_CH 3
#define H_DIM 512
#define W_DIM 512
#define PXT 4
#define BLOCK 256

__global__ __launch_bounds__(BLOCK) void dssim_kernel(
        const float* __restrict__ yp,
        const float* __restrict__ yt,
        float* __restrict__ out) {
    const int lane = threadIdx.x & 63;
    const int wave = threadIdx.x >> 6;          // 0..3
    const int half = wave & 1;                  // 0 = left half-row, 1 = right
    const int row  = blockIdx.x * 2 + (wave >> 1);  // global row in [0, N*H)
    const int h    = row & (H_DIM - 1);
    const int n    = row >> 9;
    const int w0   = half * 256 + lane * PXT;

    // accumulators for the 4 owned columns
    float aT[4], aP[4], aTT[4], aPP[4], aTP[4];
    #pragma unroll
    for (int j = 0; j < 4; ++j) { aT[j]=0.f; aP[j]=0.f; aTT[j]=0.f; aPP[j]=0.f; aTP[j]=0.f; }

    #pragma unroll
    for (int c = 0; c < C_CH; ++c) {
        #pragma unroll
        for (int dy = -1; dy <= 1; ++dy) {
            const int hh = h + dy;
            if ((unsigned)hh >= (unsigned)H_DIM) continue;  // zero-pad (wave-uniform)
            const size_t base = ((size_t)((n * C_CH + c) * H_DIM + hh)) * W_DIM + w0;

            const float4 t4 = *reinterpret_cast<const float4*>(yt + base);
            const float4 p4 = *reinterpret_cast<const float4*>(yp + base);

            const float tv[4] = {t4.x, t4.y, t4.z, t4.w};
            const float pv[4] = {p4.x, p4.y, p4.z, p4.w};
            #pragma unroll
            for (int j = 0; j < 4; ++j) {
                const float t = tv[j], p = pv[j];
                aT[j]  += t;
                aP[j]  += p;
                aTT[j] = fmaf(t, t, aTT[j]);
                aPP[j] = fmaf(p, p, aPP[j]);
                aTP[j] = fmaf(t, p, aTP[j]);
            }
        }
    }

    // cross-wave edge exchange: each wave publishes lane0's col0 sums (its left
    // edge) and lane63's col3 sums (its right edge).
    __shared__ float edgeL[4][5];
    __shared__ float edgeR[4][5];
    if (lane == 0)  { edgeL[wave][0]=aT[0]; edgeL[wave][1]=aP[0]; edgeL[wave][2]=aTT[0]; edgeL[wave][3]=aPP[0]; edgeL[wave][4]=aTP[0]; }
    if (lane == 63) { edgeR[wave][0]=aT[3]; edgeR[wave][1]=aP[3]; edgeR[wave][2]=aTT[3]; edgeR[wave][3]=aPP[3]; edgeR[wave][4]=aTP[3]; }
    __syncthreads();

    // halo column sums: left halo (col w0-1) = prev lane's col3; right halo
    // (col w0+4) = next lane's col0. Boundary lanes patch from LDS / zero.
    float lT  = __shfl_up(aT[3],  1);
    float lP  = __shfl_up(aP[3],  1);
    float lTT = __shfl_up(aTT[3], 1);
    float lPP = __shfl_up(aPP[3], 1);
    float lTP = __shfl_up(aTP[3], 1);
    float rT  = __shfl_down(aT[0],  1);
    float rP  = __shfl_down(aP[0],  1);
    float rTT = __shfl_down(aTT[0], 1);
    float rPP = __shfl_down(aPP[0], 1);
    float rTP = __shfl_down(aTP[0], 1);
    if (lane == 0) {
        if (half == 1) { lT=edgeR[wave-1][0]; lP=edgeR[wave-1][1]; lTT=edgeR[wave-1][2]; lPP=edgeR[wave-1][3]; lTP=edgeR[wave-1][4]; }
        else           { lT=0.f; lP=0.f; lTT=0.f; lPP=0.f; lTP=0.f; }
    }
    if (lane == 63) {
        if (half == 0) { rT=edgeL[wave+1][0]; rP=edgeL[wave+1][1]; rTT=edgeL[wave+1][2]; rPP=edgeL[wave+1][3]; rTP=edgeL[wave+1][4]; }
        else           { rT=0.f; rP=0.f; rTT=0.f; rPP=0.f; rTP=0.f; }
    }

    const float C1f = 1.0e-4f;       // (0.01*1)^2
    const float C2f = 9.0e-4f;       // (0.03*1)^2
    const float inv_n = 1.f / 27.f;
    const float inv_v = 1.f / 26.f;

    float lsum = 0.f;
    #pragma unroll
    for (int k = 0; k < PXT; ++k) {
        const float st  = (k == 0 ? lT  : aT[k-1])  + aT[k]  + (k == 3 ? rT  : aT[k+1]);
        const float sp  = (k == 0 ? lP  : aP[k-1])  + aP[k]  + (k == 3 ? rP  : aP[k+1]);
        const float stt = (k == 0 ? lTT : aTT[k-1]) + aTT[k] + (k == 3 ? rTT : aTT[k+1]);
        const float spp = (k == 0 ? lPP : aPP[k-1]) + aPP[k] + (k == 3 ? rPP : aPP[k+1]);
        const float stp = (k == 0 ? lTP : aTP[k-1]) + aTP[k] + (k == 3 ? rTP : aTP[k+1]);

        const float ut = st * inv_n;
        const float up = sp * inv_n;
        const float vart = (stt - st * st * inv_n) * inv_v;
        const float varp = (spp - sp * sp * inv_n) * inv_v;
        const float cov  = stp * inv_n - ut * up;

        const float num = (2.f * ut * up + C1f) * (2.f * cov + C2f);
        const float den = (ut * ut + up * up + C1f) * (vart + varp + C2f);
        lsum = fmaf(-num * __builtin_amdgcn_rcpf(den), 0.5f, lsum + 0.5f);
    }

    // wave reduction
    #pragma unroll
    for (int off = 32; off > 0; off >>= 1)
        lsum += __shfl_down(lsum, off, 64);

    __shared__ float smem[BLOCK / 64];
    if (lane == 0) smem[wave] = lsum;
    __syncthreads();
    if (threadIdx.x == 0) {
        float s = 0.f;
        #pragma unroll
        for (int i = 0; i < BLOCK / 64; ++i) s += smem[i];
        atomicAdd(out, s * (1.f / (float)(N_IMG * H_DIM * W_DIM)));
    }
}

extern "C" void kernel_launch(void* const* d_in, const int* in_sizes, int n_in,
                              void* d_out, int out_size, void* d_ws, size_t ws_size,
                              hipStream_t stream) {
    const float* yp = (const float*)d_in[0];   // y_pred
    const float* yt = (const float*)d_in[1];   // y_true
    float* out = (float*)d_out;

    hipMemsetAsync(out, 0, sizeof(float) * (size_t)out_size, stream);

    const int grid = (N_IMG * H_DIM) / 2;      // 2048 blocks, 8192 waves
    dssim_kernel<<<grid, BLOCK, 0, stream>>>(yp, yt, out);
}

// Round 5
// 34.555 us; speedup vs baseline: 1.4346x; 1.4346x over previous
//
#include <hip/hip_runtime.h>

// DSSIM loss: y_pred, y_true [8,3,512,512] fp32 -> scalar mean DSSIM.
// One wave = one full image row (64 lanes x 8 px). Interior rows (1..510)
// take a BRANCH-FREE path: 12 unconditional float4 loads per channel into
// registers, then accumulate -- lets the scheduler keep many loads in flight
// (R4 post-mortem: guarded loads pinned VGPR=24 => ~2 loads in flight =>
// 9 exposed memory latencies per wave). Edge rows use the guarded path.

#define N_IMG 8
#define C_CH 3
#define H_DIM 512
#define W_DIM 512
#define PXT 8
#define TOTAL_THREADS (N_IMG * H_DIM * 64)   // 262144
#define BLOCK 256

__device__ __forceinline__ void acc8(const float4& t0, const float4& t1,
                                     const float4& p0, const float4& p1,
                                     float* aT, float* aP, float* aTT,
                                     float* aPP, float* aTP) {
    const float tv[8] = {t0.x, t0.y, t0.z, t0.w, t1.x, t1.y, t1.z, t1.w};
    const float pv[8] = {p0.x, p0.y, p0.z, p0.w, p1.x, p1.y, p1.z, p1.w};
    #pragma unroll
    for (int j = 0; j < 8; ++j) {
        const float t = tv[j], p = pv[j];
        aT[j]  += t;
        aP[j]  += p;
        aTT[j] = fmaf(t, t, aTT[j]);
        aPP[j] = fmaf(p, p, aPP[j]);
        aTP[j] = fmaf(t, p, aTP[j]);
    }
}

__global__ __launch_bounds__(BLOCK) void dssim_kernel(
        const float* __restrict__ yp,
        const float* __restrict__ yt,
        float* __restrict__ out) {
    const int tid  = blockIdx.x * BLOCK + threadIdx.x;
    const int lane = tid & 63;
    const int r    = tid >> 6;            // row id over [N*H]
    const int h    = r & (H_DIM - 1);
    const int n    = r >> 9;
    const int w0   = lane * PXT;

    float aT[8], aP[8], aTT[8], aPP[8], aTP[8];
    #pragma unroll
    for (int j = 0; j < 8; ++j) { aT[j]=0.f; aP[j]=0.f; aTT[j]=0.f; aPP[j]=0.f; aTP[j]=0.f; }

    if (h >= 1 && h <= H_DIM - 2) {
        // fast path: all 9 (c,dy) rows exist -> unconditional loads
        #pragma unroll
        for (int c = 0; c < C_CH; ++c) {
            const float* tp = yt + ((size_t)((n * C_CH + c) * H_DIM + h)) * W_DIM + w0;
            const float* pp = yp + ((size_t)((n * C_CH + c) * H_DIM + h)) * W_DIM + w0;

            float4 t00, t01, t10, t11, t20, t21;
            float4 p00, p01, p10, p11, p20, p21;
            t00 = *reinterpret_cast<const float4*>(tp - W_DIM);
            t01 = *reinterpret_cast<const float4*>(tp - W_DIM + 4);
            t10 = *reinterpret_cast<const float4*>(tp);
            t11 = *reinterpret_cast<const float4*>(tp + 4);
            t20 = *reinterpret_cast<const float4*>(tp + W_DIM);
            t21 = *reinterpret_cast<const float4*>(tp + W_DIM + 4);
            p00 = *reinterpret_cast<const float4*>(pp - W_DIM);
            p01 = *reinterpret_cast<const float4*>(pp - W_DIM + 4);
            p10 = *reinterpret_cast<const float4*>(pp);
            p11 = *reinterpret_cast<const float4*>(pp + 4);
            p20 = *reinterpret_cast<const float4*>(pp + W_DIM);
            p21 = *reinterpret_cast<const float4*>(pp + W_DIM + 4);

            acc8(t00, t01, p00, p01, aT, aP, aTT, aPP, aTP);
            acc8(t10, t11, p10, p11, aT, aP, aTT, aPP, aTP);
            acc8(t20, t21, p20, p21, aT, aP, aTT, aPP, aTP);
        }
    } else {
        // edge rows (h==0 or h==511): guarded loads
        #pragma unroll
        for (int c = 0; c < C_CH; ++c) {
            #pragma unroll
            for (int dy = -1; dy <= 1; ++dy) {
                const int hh = h + dy;
                if ((unsigned)hh >= (unsigned)H_DIM) continue;
                const size_t base = ((size_t)((n * C_CH + c) * H_DIM + hh)) * W_DIM + w0;
                const float4 t0 = *reinterpret_cast<const float4*>(yt + base);
                const float4 t1 = *reinterpret_cast<const float4*>(yt + base + 4);
                const float4 p0 = *reinterpret_cast<const float4*>(yp + base);
                const float4 p1 = *reinterpret_cast<const float4*>(yp + base + 4);
                acc8(t0, t1, p0, p1, aT, aP, aTT, aPP, aTP);
            }
        }
    }

    // halo column sums: left halo (col w0-1) = prev lane's col7 sums;
    // right halo (col w0+8) = next lane's col0 sums. Zero at image edges.
    float lT  = __shfl_up(aT[7],  1);
    float lP  = __shfl_up(aP[7],  1);
    float lTT = __shfl_up(aTT[7], 1);
    float lPP = __shfl_up(aPP[7], 1);
    float lTP = __shfl_up(aTP[7], 1);
    float rT  = __shfl_down(aT[0],  1);
    float rP  = __shfl_down(aP[0],  1);
    float rTT = __shfl_down(aTT[0], 1);
    float rPP = __shfl_down(aPP[0], 1);
    float rTP = __shfl_down(aTP[0], 1);
    if (lane == 0)  { lT=0.f; lP=0.f; lTT=0.f; lPP=0.f; lTP=0.f; }
    if (lane == 63) { rT=0.f; rP=0.f; rTT=0.f; rPP=0.f; rTP=0.f; }

    const float C1f = 1.0e-4f;
    const float C2f = 9.0e-4f;
    const float inv_n = 1.f / 27.f;
    const float inv_v = 1.f / 26.f;

    float lsum = 0.f;
    #pragma unroll
    for (int k = 0; k < PXT; ++k) {
        const float st  = (k == 0 ? lT  : aT[k-1])  + aT[k]  + (k == 7 ? rT  : aT[k+1]);
        const float sp  = (k == 0 ? lP  : aP[k-1])  + aP[k]  + (k == 7 ? rP  : aP[k+1]);
        const float stt = (k == 0 ? lTT : aTT[k-1]) + aTT[k] + (k == 7 ? rTT : aTT[k+1]);
        const float spp = (k == 0 ? lPP : aPP[k-1]) + aPP[k] + (k == 7 ? rPP : aPP[k+1]);
        const float stp = (k == 0 ? lTP : aTP[k-1]) + aTP[k] + (k == 7 ? rTP : aTP[k+1]);

        const float ut = st * inv_n;
        const float up = sp * inv_n;
        const float vart = (stt - st * st * inv_n) * inv_v;
        const float varp = (spp - sp * sp * inv_n) * inv_v;
        const float cov  = stp * inv_n - ut * up;

        const float num = (2.f * ut * up + C1f) * (2.f * cov + C2f);
        const float den = (ut * ut + up * up + C1f) * (vart + varp + C2f);
        lsum = fmaf(-num * __builtin_amdgcn_rcpf(den), 0.5f, lsum + 0.5f);
    }

    // wave reduction
    #pragma unroll
    for (int off = 32; off > 0; off >>= 1)
        lsum += __shfl_down(lsum, off, 64);

    __shared__ float smem[BLOCK / 64];
    const int wl  = threadIdx.x & 63;
    const int wid = threadIdx.x >> 6;
    if (wl == 0) smem[wid] = lsum;
    __syncthreads();
    if (threadIdx.x == 0) {
        float s = 0.f;
        #pragma unroll
        for (int i = 0; i < BLOCK / 64; ++i) s += smem[i];
        atomicAdd(out, s * (1.f / (float)(N_IMG * H_DIM * W_DIM)));
    }
}

extern "C" void kernel_launch(void* const* d_in, const int* in_sizes, int n_in,
                              void* d_out, int out_size, void* d_ws, size_t ws_size,
                              hipStream_t stream) {
    const float* yp = (const float*)d_in[0];   // y_pred
    const float* yt = (const float*)d_in[1];   // y_true
    float* out = (float*)d_out;

    hipMemsetAsync(out, 0, sizeof(float) * (size_t)out_size, stream);

    const int grid = TOTAL_THREADS / BLOCK;    // 1024 blocks
    dssim_kernel<<<grid, BLOCK, 0, stream>>>(yp, yt, out);
}

// Round 6
// 28.441 us; speedup vs baseline: 1.7430x; 1.2150x over previous
//
#include <hip/hip_runtime.h>

// DSSIM loss: y_pred, y_true [8,3,512,512] fp32 -> scalar mean DSSIM.
// R6: cut vector-memory DELIVERED bytes (the R2-R5 invariant wall: ~147MB
// @ ~5.25 TB/s). Thread owns 4 cols x 4 output rows: loads 6 input rows
// (24 float4) for 16 px -> 1.5x vertical over-read instead of 3x (~74 MB).
// Vertical window reuse in registers; horizontal halo via one post-loop
// shfl of accumulated window sums + LDS patch at half-row boundaries.

#define N_IMG 8
#define C_CH 3
#define H_DIM 512
#define W_DIM 512
#define BLOCK 256
// wave = 64 lanes x 4 cols = 256 cols (half width) x 4 rows (one band)
// block = 4 waves = 2 bands x 2 halves; bands = 8*128 = 1024; grid = 512

__global__ __launch_bounds__(BLOCK) void dssim_kernel(
        const float* __restrict__ yp,
        const float* __restrict__ yt,
        float* __restrict__ out) {
    const int lane = threadIdx.x & 63;
    const int wave = threadIdx.x >> 6;            // 0..3
    const int half = wave & 1;                    // 0 = left half, 1 = right
    const int band = blockIdx.x * 2 + (wave >> 1);// 0..1023
    const int n    = band >> 7;                   // image
    const int bimg = band & 127;                  // band within image
    const int h0   = bimg << 2;                   // first output row
    const int w0   = half * 256 + lane * 4;

    const bool topOK = (bimg != 0);
    const bool botOK = (bimg != 127);

    // window sums [outrow][stat][col]; stats: T, P, TT, PP, TP
    float wS[4][5][4];
    #pragma unroll
    for (int o = 0; o < 4; ++o)
        #pragma unroll
        for (int s = 0; s < 5; ++s)
            #pragma unroll
            for (int j = 0; j < 4; ++j) wS[o][s][j] = 0.f;

    #pragma unroll
    for (int c = 0; c < C_CH; ++c) {
        const size_t rb = ((size_t)((n * C_CH + c) * H_DIM + h0)) * W_DIM + w0;

        float4 t[6], p[6];   // ri: 0 -> row h0-1 ... 5 -> row h0+4
        if (topOK) { t[0] = *(const float4*)(yt + rb - W_DIM);
                     p[0] = *(const float4*)(yp + rb - W_DIM); }
        else       { t[0] = make_float4(0.f,0.f,0.f,0.f);
                     p[0] = make_float4(0.f,0.f,0.f,0.f); }
        t[1] = *(const float4*)(yt + rb);
        p[1] = *(const float4*)(yp + rb);
        t[2] = *(const float4*)(yt + rb + W_DIM);
        p[2] = *(const float4*)(yp + rb + W_DIM);
        t[3] = *(const float4*)(yt + rb + 2 * W_DIM);
        p[3] = *(const float4*)(yp + rb + 2 * W_DIM);
        t[4] = *(const float4*)(yt + rb + 3 * W_DIM);
        p[4] = *(const float4*)(yp + rb + 3 * W_DIM);
        if (botOK) { t[5] = *(const float4*)(yt + rb + 4 * W_DIM);
                     p[5] = *(const float4*)(yp + rb + 4 * W_DIM); }
        else       { t[5] = make_float4(0.f,0.f,0.f,0.f);
                     p[5] = make_float4(0.f,0.f,0.f,0.f); }

        // input row ri (global h0-1+ri) feeds output rows o in [ri-2, ri] ∩ [0,3]
        #pragma unroll
        for (int ri = 0; ri < 6; ++ri) {
            const float tv[4] = {t[ri].x, t[ri].y, t[ri].z, t[ri].w};
            const float pv[4] = {p[ri].x, p[ri].y, p[ri].z, p[ri].w};
            #pragma unroll
            for (int j = 0; j < 4; ++j) {
                const float tj = tv[j], pj = pv[j];
                const float tt = tj * tj, pp = pj * pj, tp = tj * pj;
                #pragma unroll
                for (int o = 0; o < 4; ++o) {
                    if (o >= ri - 2 && o <= ri) {   // compile-time folds
                        wS[o][0][j] += tj;
                        wS[o][1][j] += pj;
                        wS[o][2][j] += tt;
                        wS[o][3][j] += pp;
                        wS[o][4][j] += tp;
                    }
                }
            }
        }
    }

    // cross-wave edge publish: lane0 col0 / lane63 col3 window sums
    __shared__ float eL[4][4][5];
    __shared__ float eR[4][4][5];
    if (lane == 0) {
        #pragma unroll
        for (int o = 0; o < 4; ++o)
            #pragma unroll
            for (int s = 0; s < 5; ++s) eL[wave][o][s] = wS[o][s][0];
    }
    if (lane == 63) {
        #pragma unroll
        for (int o = 0; o < 4; ++o)
            #pragma unroll
            for (int s = 0; s < 5; ++s) eR[wave][o][s] = wS[o][s][3];
    }
    __syncthreads();

    // halo window sums: left (col w0-1) = prev lane col3; right (col w0+4) = next lane col0
    float lh[4][5], rh[4][5];
    #pragma unroll
    for (int o = 0; o < 4; ++o)
        #pragma unroll
        for (int s = 0; s < 5; ++s) {
            lh[o][s] = __shfl_up(wS[o][s][3], 1);
            rh[o][s] = __shfl_down(wS[o][s][0], 1);
        }
    if (lane == 0) {
        #pragma unroll
        for (int o = 0; o < 4; ++o)
            #pragma unroll
            for (int s = 0; s < 5; ++s)
                lh[o][s] = (half == 1) ? eR[wave - 1][o][s] : 0.f;
    }
    if (lane == 63) {
        #pragma unroll
        for (int o = 0; o < 4; ++o)
            #pragma unroll
            for (int s = 0; s < 5; ++s)
                rh[o][s] = (half == 0) ? eL[wave + 1][o][s] : 0.f;
    }

    const float C1f = 1.0e-4f;
    const float C2f = 9.0e-4f;
    const float inv_n = 1.f / 27.f;
    const float inv_v = 1.f / 26.f;

    float lsum = 0.f;
    #pragma unroll
    for (int o = 0; o < 4; ++o) {
        #pragma unroll
        for (int k = 0; k < 4; ++k) {
            const float st  = (k==0 ? lh[o][0] : wS[o][0][k-1]) + wS[o][0][k] + (k==3 ? rh[o][0] : wS[o][0][k+1]);
            const float sp  = (k==0 ? lh[o][1] : wS[o][1][k-1]) + wS[o][1][k] + (k==3 ? rh[o][1] : wS[o][1][k+1]);
            const float stt = (k==0 ? lh[o][2] : wS[o][2][k-1]) + wS[o][2][k] + (k==3 ? rh[o][2] : wS[o][2][k+1]);
            const float spp = (k==0 ? lh[o][3] : wS[o][3][k-1]) + wS[o][3][k] + (k==3 ? rh[o][3] : wS[o][3][k+1]);
            const float stp = (k==0 ? lh[o][4] : wS[o][4][k-1]) + wS[o][4][k] + (k==3 ? rh[o][4] : wS[o][4][k+1]);

            const float ut = st * inv_n;
            const float up = sp * inv_n;
            const float vart = (stt - st * st * inv_n) * inv_v;
            const float varp = (spp - sp * sp * inv_n) * inv_v;
            const float cov  = stp * inv_n - ut * up;

            const float num = (2.f * ut * up + C1f) * (2.f * cov + C2f);
            const float den = (ut * ut + up * up + C1f) * (vart + varp + C2f);
            lsum = fmaf(-num * __builtin_amdgcn_rcpf(den), 0.5f, lsum + 0.5f);
        }
    }

    // wave reduction
    #pragma unroll
    for (int off = 32; off > 0; off >>= 1)
        lsum += __shfl_down(lsum, off, 64);

    __shared__ float smem[BLOCK / 64];
    if (lane == 0) smem[wave] = lsum;
    __syncthreads();
    if (threadIdx.x == 0) {
        float s = 0.f;
        #pragma unroll
        for (int i = 0; i < BLOCK / 64; ++i) s += smem[i];
        atomicAdd(out, s * (1.f / (float)(N_IMG * H_DIM * W_DIM)));
    }
}

extern "C" void kernel_launch(void* const* d_in, const int* in_sizes, int n_in,
                              void* d_out, int out_size, void* d_ws, size_t ws_size,
                              hipStream_t stream) {
    const float* yp = (const float*)d_in[0];   // y_pred
    const float* yt = (const float*)d_in[1];   // y_true
    float* out = (float*)d_out;

    hipMemsetAsync(out, 0, sizeof(float) * (size_t)out_size, stream);

    const int grid = (N_IMG * (H_DIM / 4) * 2) / 4;   // 512 blocks
    dssim_kernel<<<grid, BLOCK, 0, stream>>>(yp, yt, out);
}

// Round 7
// 21.469 us; speedup vs baseline: 2.3090x; 1.3247x over previous
//
#include <hip/hip_runtime.h>

// DSSIM loss: y_pred, y_true [8,3,512,512] fp32 -> scalar mean DSSIM.
// R7: R6 tiling (thread = 4 cols x 4 output rows, 6 input rows, 1.5x bytes)
// PLUS: (a) __launch_bounds__(256,2) so the compiler may use ~256 VGPR,
// (b) preload ALL 36 float4 into named arrays then accumulate (straight-line,
// no branches between loads -> loads issue back-to-back, latencies overlap;
// R2-R6 post-mortem: compiler was sinking loads, serializing ~36 x ~1300cyc),
// (c) no hipMemsetAsync/atomic: per-block partials to d_ws + tiny reduce kernel.

#define N_IMG 8
#define C_CH 3
#define H_DIM 512
#define W_DIM 512
#define BLOCK 256
#define GRID 512        // 1024 bands x 2 halves / 4 waves per block

__global__ __launch_bounds__(BLOCK, 2) void dssim_partial(
        const float* __restrict__ yp,
        const float* __restrict__ yt,
        float* __restrict__ ws) {
    const int lane = threadIdx.x & 63;
    const int wave = threadIdx.x >> 6;            // 0..3
    const int half = wave & 1;                    // 0 = left half, 1 = right
    const int band = blockIdx.x * 2 + (wave >> 1);// 0..1023
    const int n    = band >> 7;
    const int bimg = band & 127;
    const int h0   = bimg << 2;                   // first output row
    const int w0   = half * 256 + lane * 4;

    // ---- preload all 36 float4 (3 ch x 6 rows x 2 tensors) ----
    float4 T[3][6], P[3][6];
    const bool interior = (bimg != 0) && (bimg != 127);
    if (interior) {
        #pragma unroll
        for (int c = 0; c < C_CH; ++c) {
            const size_t rb = ((size_t)((n * C_CH + c) * H_DIM + h0)) * W_DIM + w0;
            #pragma unroll
            for (int ri = 0; ri < 6; ++ri) {
                const size_t a = rb + (size_t)(ri - 1) * W_DIM;
                T[c][ri] = *(const float4*)(yt + a);
                P[c][ri] = *(const float4*)(yp + a);
            }
        }
    } else {
        // edge bands: clamp row address (always in-bounds), zero-select after
        #pragma unroll
        for (int c = 0; c < C_CH; ++c) {
            const size_t cb = ((size_t)((n * C_CH + c) * H_DIM)) * W_DIM + w0;
            #pragma unroll
            for (int ri = 0; ri < 6; ++ri) {
                const int hh = h0 - 1 + ri;
                const int hc = hh < 0 ? 0 : (hh > H_DIM - 1 ? H_DIM - 1 : hh);
                const size_t a = cb + (size_t)hc * W_DIM;
                float4 t = *(const float4*)(yt + a);
                float4 p = *(const float4*)(yp + a);
                if (hh != hc) { t = make_float4(0.f,0.f,0.f,0.f);
                                p = make_float4(0.f,0.f,0.f,0.f); }
                T[c][ri] = t;
                P[c][ri] = p;
            }
        }
    }

    // ---- accumulate window sums [outrow][stat][col] ----
    float wS[4][5][4];
    #pragma unroll
    for (int o = 0; o < 4; ++o)
        #pragma unroll
        for (int s = 0; s < 5; ++s)
            #pragma unroll
            for (int j = 0; j < 4; ++j) wS[o][s][j] = 0.f;

    #pragma unroll
    for (int c = 0; c < C_CH; ++c) {
        #pragma unroll
        for (int ri = 0; ri < 6; ++ri) {
            const float tv[4] = {T[c][ri].x, T[c][ri].y, T[c][ri].z, T[c][ri].w};
            const float pv[4] = {P[c][ri].x, P[c][ri].y, P[c][ri].z, P[c][ri].w};
            #pragma unroll
            for (int j = 0; j < 4; ++j) {
                const float tj = tv[j], pj = pv[j];
                const float tt = tj * tj, pp = pj * pj, tp = tj * pj;
                #pragma unroll
                for (int o = 0; o < 4; ++o) {
                    if (o >= ri - 2 && o <= ri) {   // compile-time folds
                        wS[o][0][j] += tj;
                        wS[o][1][j] += pj;
                        wS[o][2][j] += tt;
                        wS[o][3][j] += pp;
                        wS[o][4][j] += tp;
                    }
                }
            }
        }
    }

    // ---- cross-wave edge publish (half-row boundary) ----
    __shared__ float eL[4][4][5];
    __shared__ float eR[4][4][5];
    if (lane == 0) {
        #pragma unroll
        for (int o = 0; o < 4; ++o)
            #pragma unroll
            for (int s = 0; s < 5; ++s) eL[wave][o][s] = wS[o][s][0];
    }
    if (lane == 63) {
        #pragma unroll
        for (int o = 0; o < 4; ++o)
            #pragma unroll
            for (int s = 0; s < 5; ++s) eR[wave][o][s] = wS[o][s][3];
    }
    __syncthreads();

    // ---- halo window sums via one post-loop shfl ----
    float lh[4][5], rh[4][5];
    #pragma unroll
    for (int o = 0; o < 4; ++o)
        #pragma unroll
        for (int s = 0; s < 5; ++s) {
            lh[o][s] = __shfl_up(wS[o][s][3], 1);
            rh[o][s] = __shfl_down(wS[o][s][0], 1);
        }
    if (lane == 0) {
        #pragma unroll
        for (int o = 0; o < 4; ++o)
            #pragma unroll
            for (int s = 0; s < 5; ++s)
                lh[o][s] = (half == 1) ? eR[wave - 1][o][s] : 0.f;
    }
    if (lane == 63) {
        #pragma unroll
        for (int o = 0; o < 4; ++o)
            #pragma unroll
            for (int s = 0; s < 5; ++s)
                rh[o][s] = (half == 0) ? eL[wave + 1][o][s] : 0.f;
    }

    const float C1f = 1.0e-4f;
    const float C2f = 9.0e-4f;
    const float inv_n = 1.f / 27.f;
    const float inv_v = 1.f / 26.f;

    float lsum = 0.f;
    #pragma unroll
    for (int o = 0; o < 4; ++o) {
        #pragma unroll
        for (int k = 0; k < 4; ++k) {
            const float st  = (k==0 ? lh[o][0] : wS[o][0][k-1]) + wS[o][0][k] + (k==3 ? rh[o][0] : wS[o][0][k+1]);
            const float sp  = (k==0 ? lh[o][1] : wS[o][1][k-1]) + wS[o][1][k] + (k==3 ? rh[o][1] : wS[o][1][k+1]);
            const float stt = (k==0 ? lh[o][2] : wS[o][2][k-1]) + wS[o][2][k] + (k==3 ? rh[o][2] : wS[o][2][k+1]);
            const float spp = (k==0 ? lh[o][3] : wS[o][3][k-1]) + wS[o][3][k] + (k==3 ? rh[o][3] : wS[o][3][k+1]);
            const float stp = (k==0 ? lh[o][4] : wS[o][4][k-1]) + wS[o][4][k] + (k==3 ? rh[o][4] : wS[o][4][k+1]);

            const float ut = st * inv_n;
            const float up = sp * inv_n;
            const float vart = (stt - st * st * inv_n) * inv_v;
            const float varp = (spp - sp * sp * inv_n) * inv_v;
            const float cov  = stp * inv_n - ut * up;

            const float num = (2.f * ut * up + C1f) * (2.f * cov + C2f);
            const float den = (ut * ut + up * up + C1f) * (vart + varp + C2f);
            lsum = fmaf(-num * __builtin_amdgcn_rcpf(den), 0.5f, lsum + 0.5f);
        }
    }

    // ---- block reduction -> per-block partial ----
    #pragma unroll
    for (int off = 32; off > 0; off >>= 1)
        lsum += __shfl_down(lsum, off, 64);

    __shared__ float smem[BLOCK / 64];
    if (lane == 0) smem[wave] = lsum;
    __syncthreads();
    if (threadIdx.x == 0) {
        float s = 0.f;
        #pragma unroll
        for (int i = 0; i < BLOCK / 64; ++i) s += smem[i];
        ws[blockIdx.x] = s;
    }
}

__global__ __launch_bounds__(256) void dssim_reduce(
        const float* __restrict__ ws, float* __restrict__ out) {
    const int t = threadIdx.x;
    float s = ws[t] + ws[t + 256];     // 512 partials
    #pragma unroll
    for (int off = 32; off > 0; off >>= 1)
        s += __shfl_down(s, off, 64);
    __shared__ float smem[4];
    const int lane = t & 63, wave = t >> 6;
    if (lane == 0) smem[wave] = s;
    __syncthreads();
    if (t == 0) {
        float tot = smem[0] + smem[1] + smem[2] + smem[3];
        out[0] = tot * (1.f / (float)(N_IMG * H_DIM * W_DIM));
    }
}

extern "C" void kernel_launch(void* const* d_in, const int* in_sizes, int n_in,
                              void* d_out, int out_size, void* d_ws, size_t ws_size,
                              hipStream_t stream) {
    const float* yp = (const float*)d_in[0];   // y_pred
    const float* yt = (const float*)d_in[1];   // y_true
    float* out = (float*)d_out;
    float* ws  = (float*)d_ws;

    dssim_partial<<<GRID, BLOCK, 0, stream>>>(yp, yt, ws);
    dssim_reduce<<<1, 256, 0, stream>>>(ws, out);
}

// Round 8
// 20.978 us; speedup vs baseline: 2.3630x; 1.0234x over previous
//
#include <hip/hip_runtime.h>

// DSSIM loss: y_pred, y_true [8,3,512,512] fp32 -> scalar mean DSSIM.
// R8: eliminate vertical over-read. Thread = 4 cols x 4 rows; each input row
// is loaded ONCE and reduced to per-row column sums rS[4][5][4]; the
// rowsum[h0-1]/rowsum[h0+4] needed for vertical 3-row windows come from the
// vertically-adjacent wave via LDS (pub, 2 phases), not from re-loading rows.
// Block = 512 thr = 8 waves = 16 rows x 512 cols; only the block's top/bottom
// halo rows are re-loaded -> over-read 18/16 = 1.125x (was 1.5x): ~56.6 MB.
// Horizontal halo: post-hoc shfl of window sums + eL/eR LDS patch (as R7).

#define N_IMG 8
#define C_CH 3
#define H_DIM 512
#define W_DIM 512
#define BLOCK 512
#define GRID 256   // 8 img x 32 bands of 16 rows; 1 block per CU

__global__ __launch_bounds__(BLOCK, 2) void dssim_partial(
        const float* __restrict__ yp,
        const float* __restrict__ yt,
        float* __restrict__ ws) {
    const int tid   = threadIdx.x;
    const int lane  = tid & 63;
    const int wv    = tid >> 6;         // 0..7
    const int g     = wv >> 1;          // vertical row-group 0..3
    const int half  = wv & 1;           // 0 = cols [0,256), 1 = [256,512)
    const int b     = blockIdx.x;
    const int n     = b >> 5;           // image
    const int vb    = b & 31;           // band within image
    const int hbase = vb << 4;          // band top row
    const int h0    = hbase + (g << 2); // thread's first owned row
    const int w0    = half * 256 + lane * 4;

    // ---- preload owned rows (24 float4, straight-line) ----
    float4 T[3][4], P[3][4];
    #pragma unroll
    for (int c = 0; c < C_CH; ++c) {
        const size_t rb = ((size_t)((n * C_CH + c) * H_DIM + h0)) * W_DIM + w0;
        #pragma unroll
        for (int r = 0; r < 4; ++r) {
            T[c][r] = *(const float4*)(yt + rb + (size_t)r * W_DIM);
            P[c][r] = *(const float4*)(yp + rb + (size_t)r * W_DIM);
        }
    }

    // ---- halo row sums (band-boundary rows; only g==0 / g==3 use) ----
    // stat order: 0=T 1=P 2=TT 3=PP 4=TP
    float rH[5][4];
    #pragma unroll
    for (int s = 0; s < 5; ++s)
        #pragma unroll
        for (int j = 0; j < 4; ++j) rH[s][j] = 0.f;
    if (g == 0 || g == 3) {                      // wave-uniform
        const bool have = (g == 0) ? (vb != 0) : (vb != 31);
        const int  hh   = (g == 0) ? (hbase - 1) : (hbase + 16);
        if (have) {                              // wave-uniform
            #pragma unroll
            for (int c = 0; c < C_CH; ++c) {
                const size_t a = ((size_t)((n * C_CH + c) * H_DIM + hh)) * W_DIM + w0;
                const float4 t = *(const float4*)(yt + a);
                const float4 p = *(const float4*)(yp + a);
                const float tv[4] = {t.x, t.y, t.z, t.w};
                const float pv[4] = {p.x, p.y, p.z, p.w};
                #pragma unroll
                for (int j = 0; j < 4; ++j) {
                    rH[0][j] += tv[j];
                    rH[1][j] += pv[j];
                    rH[2][j] = fmaf(tv[j], tv[j], rH[2][j]);
                    rH[3][j] = fmaf(pv[j], pv[j], rH[3][j]);
                    rH[4][j] = fmaf(tv[j], pv[j], rH[4][j]);
                }
            }
        }
    }

    // ---- per-row column sums for owned rows ----
    float rS[4][5][4];
    #pragma unroll
    for (int r = 0; r < 4; ++r)
        #pragma unroll
        for (int s = 0; s < 5; ++s)
            #pragma unroll
            for (int j = 0; j < 4; ++j) rS[r][s][j] = 0.f;

    #pragma unroll
    for (int c = 0; c < C_CH; ++c) {
        #pragma unroll
        for (int r = 0; r < 4; ++r) {
            const float tv[4] = {T[c][r].x, T[c][r].y, T[c][r].z, T[c][r].w};
            const float pv[4] = {P[c][r].x, P[c][r].y, P[c][r].z, P[c][r].w};
            #pragma unroll
            for (int j = 0; j < 4; ++j) {
                rS[r][0][j] += tv[j];
                rS[r][1][j] += pv[j];
                rS[r][2][j] = fmaf(tv[j], tv[j], rS[r][2][j]);
                rS[r][3][j] = fmaf(pv[j], pv[j], rS[r][3][j]);
                rS[r][4][j] = fmaf(tv[j], pv[j], rS[r][4][j]);
            }
        }
    }

    // ---- vertical rowsum exchange via LDS (k-major: conflict-free) ----
    __shared__ float pub[20][BLOCK];
    // phase A: publish bottom rowsum rS[3]; reader = group g+1 (its rPrev)
    #pragma unroll
    for (int s = 0; s < 5; ++s)
        #pragma unroll
        for (int j = 0; j < 4; ++j) pub[s * 4 + j][tid] = rS[3][s][j];
    __syncthreads();
    float rPrev[5][4];
    if (g > 0) {
        const int src = ((g - 1) * 2 + half) * 64 + lane;
        #pragma unroll
        for (int s = 0; s < 5; ++s)
            #pragma unroll
            for (int j = 0; j < 4; ++j) rPrev[s][j] = pub[s * 4 + j][src];
    } else {
        #pragma unroll
        for (int s = 0; s < 5; ++s)
            #pragma unroll
            for (int j = 0; j < 4; ++j) rPrev[s][j] = rH[s][j];
    }
    __syncthreads();
    // phase B: publish top rowsum rS[0]; reader = group g-1 (its rNext)
    #pragma unroll
    for (int s = 0; s < 5; ++s)
        #pragma unroll
        for (int j = 0; j < 4; ++j) pub[s * 4 + j][tid] = rS[0][s][j];
    __syncthreads();
    float rNext[5][4];
    if (g < 3) {
        const int src = ((g + 1) * 2 + half) * 64 + lane;
        #pragma unroll
        for (int s = 0; s < 5; ++s)
            #pragma unroll
            for (int j = 0; j < 4; ++j) rNext[s][j] = pub[s * 4 + j][src];
    } else {
        #pragma unroll
        for (int s = 0; s < 5; ++s)
            #pragma unroll
            for (int j = 0; j < 4; ++j) rNext[s][j] = rH[s][j];
    }

    // ---- vertical 3-row window sums ----
    float wS[4][5][4];
    #pragma unroll
    for (int s = 0; s < 5; ++s)
        #pragma unroll
        for (int j = 0; j < 4; ++j) {
            wS[0][s][j] = rPrev[s][j] + rS[0][s][j] + rS[1][s][j];
            wS[1][s][j] = rS[0][s][j] + rS[1][s][j] + rS[2][s][j];
            wS[2][s][j] = rS[1][s][j] + rS[2][s][j] + rS[3][s][j];
            wS[3][s][j] = rS[2][s][j] + rS[3][s][j] + rNext[s][j];
        }

    // ---- horizontal halo: edge publish + post-hoc shfl ----
    __shared__ float eL[8][4][5];
    __shared__ float eR[8][4][5];
    if (lane == 0) {
        #pragma unroll
        for (int o = 0; o < 4; ++o)
            #pragma unroll
            for (int s = 0; s < 5; ++s) eL[wv][o][s] = wS[o][s][0];
    }
    if (lane == 63) {
        #pragma unroll
        for (int o = 0; o < 4; ++o)
            #pragma unroll
            for (int s = 0; s < 5; ++s) eR[wv][o][s] = wS[o][s][3];
    }
    __syncthreads();

    float lh[4][5], rh[4][5];
    #pragma unroll
    for (int o = 0; o < 4; ++o)
        #pragma unroll
        for (int s = 0; s < 5; ++s) {
            lh[o][s] = __shfl_up(wS[o][s][3], 1);
            rh[o][s] = __shfl_down(wS[o][s][0], 1);
        }
    if (lane == 0) {
        #pragma unroll
        for (int o = 0; o < 4; ++o)
            #pragma unroll
            for (int s = 0; s < 5; ++s)
                lh[o][s] = (half == 1) ? eR[wv - 1][o][s] : 0.f;
    }
    if (lane == 63) {
        #pragma unroll
        for (int o = 0; o < 4; ++o)
            #pragma unroll
            for (int s = 0; s < 5; ++s)
                rh[o][s] = (half == 0) ? eL[wv + 1][o][s] : 0.f;
    }

    // ---- SSIM epilogue ----
    const float C1f = 1.0e-4f;
    const float C2f = 9.0e-4f;
    const float inv_n = 1.f / 27.f;
    const float inv_v = 1.f / 26.f;

    float lsum = 0.f;
    #pragma unroll
    for (int o = 0; o < 4; ++o) {
        #pragma unroll
        for (int k = 0; k < 4; ++k) {
            const float st  = (k==0 ? lh[o][0] : wS[o][0][k-1]) + wS[o][0][k] + (k==3 ? rh[o][0] : wS[o][0][k+1]);
            const float sp  = (k==0 ? lh[o][1] : wS[o][1][k-1]) + wS[o][1][k] + (k==3 ? rh[o][1] : wS[o][1][k+1]);
            const float stt = (k==0 ? lh[o][2] : wS[o][2][k-1]) + wS[o][2][k] + (k==3 ? rh[o][2] : wS[o][2][k+1]);
            const float spp = (k==0 ? lh[o][3] : wS[o][3][k-1]) + wS[o][3][k] + (k==3 ? rh[o][3] : wS[o][3][k+1]);
            const float stp = (k==0 ? lh[o][4] : wS[o][4][k-1]) + wS[o][4][k] + (k==3 ? rh[o][4] : wS[o][4][k+1]);

            const float ut = st * inv_n;
            const float up = sp * inv_n;
            const float vart = (stt - st * st * inv_n) * inv_v;
            const float varp = (spp - sp * sp * inv_n) * inv_v;
            const float cov  = stp * inv_n - ut * up;

            const float num = (2.f * ut * up + C1f) * (2.f * cov + C2f);
            const float den = (ut * ut + up * up + C1f) * (vart + varp + C2f);
            lsum = fmaf(-num * __builtin_amdgcn_rcpf(den), 0.5f, lsum + 0.5f);
        }
    }

    // ---- block reduction -> per-block partial ----
    #pragma unroll
    for (int off = 32; off > 0; off >>= 1)
        lsum += __shfl_down(lsum, off, 64);

    __shared__ float smem[BLOCK / 64];
    if (lane == 0) smem[wv] = lsum;
    __syncthreads();
    if (tid == 0) {
        float s = 0.f;
        #pragma unroll
        for (int i = 0; i < BLOCK / 64; ++i) s += smem[i];
        ws[blockIdx.x] = s;
    }
}

__global__ __launch_bounds__(256) void dssim_reduce(
        const float* __restrict__ ws, float* __restrict__ out) {
    const int t = threadIdx.x;
    float s = ws[t];                    // 256 partials, 256 threads
    #pragma unroll
    for (int off = 32; off > 0; off >>= 1)
        s += __shfl_down(s, off, 64);
    __shared__ float smem[4];
    const int lane = t & 63, wv = t >> 6;
    if (lane == 0) smem[wv] = s;
    __syncthreads();
    if (t == 0) {
        const float tot = smem[0] + smem[1] + smem[2] + smem[3];
        out[0] = tot * (1.f / (float)(N_IMG * H_DIM * W_DIM));
    }
}

extern "C" void kernel_launch(void* const* d_in, const int* in_sizes, int n_in,
                              void* d_out, int out_size, void* d_ws, size_t ws_size,
                              hipStream_t stream) {
    const float* yp = (const float*)d_in[0];   // y_pred
    const float* yt = (const float*)d_in[1];   // y_true
    float* out = (float*)d_out;
    float* ws  = (float*)d_ws;

    dssim_partial<<<GRID, BLOCK, 0, stream>>>(yp, yt, ws);
    dssim_reduce<<<1, 256, 0, stream>>>(ws, out);
}